// Round 1
// baseline (217.702 us; speedup 1.0000x reference)
//
#include <hip/hip_runtime.h>
#include <hip/hip_bf16.h>

// BagOfWords: inputs [1024, 512] int32 tokens in [0, 50257).
// Output [1024, 50256] float32: per-row histogram over vocab, bin 0 dropped.
// Row stride of output is V-1 = 50256; token t (t>=1) goes to col t-1.

#define BATCH 1024
#define SEQ 512
#define VOCAB 50257
#define OUT_COLS (VOCAB - 1)  // 50256

__global__ void bow_scatter_kernel(const int* __restrict__ tokens,
                                   float* __restrict__ out) {
    int idx = blockIdx.x * blockDim.x + threadIdx.x;  // one thread per token
    if (idx >= BATCH * SEQ) return;
    int b = idx >> 9;           // idx / 512
    int tok = tokens[idx];
    if (tok != 0) {
        atomicAdd(&out[(long long)b * OUT_COLS + (tok - 1)], 1.0f);
    }
}

extern "C" void kernel_launch(void* const* d_in, const int* in_sizes, int n_in,
                              void* d_out, int out_size, void* d_ws, size_t ws_size,
                              hipStream_t stream) {
    const int* tokens = (const int*)d_in[0];
    float* out = (float*)d_out;

    // d_out is re-poisoned to 0xAA before every timed launch — zero it.
    // hipMemsetAsync is graph-capture safe (the harness itself uses it).
    hipMemsetAsync(out, 0, (size_t)out_size * sizeof(float), stream);

    const int total = BATCH * SEQ;          // 524288 tokens
    const int block = 256;
    const int grid = (total + block - 1) / block;  // 2048 blocks
    bow_scatter_kernel<<<grid, block, 0, stream>>>(tokens, out);
}

// Round 2
// 198.186 us; speedup vs baseline: 1.0985x; 1.0985x over previous
//
#include <hip/hip_runtime.h>
#include <hip/hip_bf16.h>

// BagOfWords: input [1024, 512] int32 tokens in [0, 50257).
// Output [1024, 50256] float32: per-row histogram, vocab bin 0 dropped.
//
// Strategy: one block per (row, 8192-col chunk). Build chunk histogram in
// LDS (32 KB) from the row's 512 tokens, then write the chunk out with
// coalesced float4 stores — zeros and counts in a single pass. No global
// atomics, no separate memset (the rocclr fill kernel writes 4x the buffer
// in HBM traffic — measured 804096 KB for a 201024 KB buffer).

#define BATCH 1024
#define SEQ 512
#define VOCAB 50257
#define OUT_COLS (VOCAB - 1)   // 50256
#define CHUNK 8192
#define NBLK_PER_ROW ((OUT_COLS + CHUNK - 1) / CHUNK)  // 7
#define BLOCK 256

__global__ __launch_bounds__(BLOCK) void bow_fused_kernel(
    const int* __restrict__ tokens, float* __restrict__ out) {
    __shared__ unsigned int hist[CHUNK];  // 32 KB

    const int c0 = blockIdx.x * CHUNK;    // chunk start col (in dropped-bin space)
    const int b  = blockIdx.y;            // row
    const int t  = threadIdx.x;

    // Zero the LDS histogram: 8192 / 256 = 32 stores/thread.
    #pragma unroll
    for (int i = t; i < CHUNK; i += BLOCK) hist[i] = 0u;
    __syncthreads();

    // Scan this row's 512 tokens (int2 per thread). Token tok maps to output
    // col tok-1; tok==0 is dropped (underflows the unsigned range check).
    const int2* trow = (const int2*)(tokens + b * SEQ);
    int2 tk = trow[t];
    unsigned int c;
    c = (unsigned int)(tk.x - 1 - c0);
    if (c < CHUNK) atomicAdd(&hist[c], 1u);
    c = (unsigned int)(tk.y - 1 - c0);
    if (c < CHUNK) atomicAdd(&hist[c], 1u);
    __syncthreads();

    // Stream the chunk to global: coalesced float4 stores.
    // Full chunks write 8192 cols; the last chunk writes 50256 - 6*8192 = 1104.
    float* orow = out + (size_t)b * OUT_COLS + c0;
    const int ncols = min(CHUNK, OUT_COLS - c0);   // 8192 or 1104 (both %4==0)
    for (int i = t * 4; i < ncols; i += BLOCK * 4) {
        uint4 h = *(const uint4*)&hist[i];
        float4 v = make_float4((float)h.x, (float)h.y, (float)h.z, (float)h.w);
        *(float4*)(orow + i) = v;
    }
}

extern "C" void kernel_launch(void* const* d_in, const int* in_sizes, int n_in,
                              void* d_out, int out_size, void* d_ws, size_t ws_size,
                              hipStream_t stream) {
    const int* tokens = (const int*)d_in[0];
    float* out = (float*)d_out;

    dim3 grid(NBLK_PER_ROW, BATCH);   // (7, 1024) = 7168 blocks
    bow_fused_kernel<<<grid, BLOCK, 0, stream>>>(tokens, out);
}